// Round 1
// baseline (637.551 us; speedup 1.0000x reference)
//
#include <hip/hip_runtime.h>
#include <math.h>

#define NPTS  50000
#define NSP   4000
#define NGRP  1000          // NSP/4 candidate quads
#define KNN   11
#define BIG   3.4e38f
#define CAP   1024          // shortlist capacity (float4 entries = 16 KiB LDS)
#define GRIDC 32
#define NKEY  65536         // 2 batches * 32^3 cells

#define MED3(a,b,c) __builtin_amdgcn_fmed3f((a),(b),(c))

// Static scratch (no reliance on d_ws): counting-sort hist/offsets + sorted points.
__device__ unsigned g_hist[NKEY];
__device__ float4   g_sorted[2 * NPTS];   // (x,y,z, orig_idx_bits), batch-major

static __device__ __forceinline__ unsigned spread5(unsigned v) {
    return (v & 1u) | ((v & 2u) << 2) | ((v & 4u) << 4) |
           ((v & 8u) << 6) | ((v & 16u) << 8);
}

static __device__ __forceinline__ unsigned cell_key(int b, float x, float y, float z) {
    int gx = (int)floorf((x + 4.0f) * 4.0f);   // [-4,4) -> [0,32), clamped
    int gy = (int)floorf((y + 4.0f) * 4.0f);
    int gz = (int)floorf((z + 4.0f) * 4.0f);
    gx = min(max(gx, 0), GRIDC - 1);
    gy = min(max(gy, 0), GRIDC - 1);
    gz = min(max(gz, 0), GRIDC - 1);
    unsigned m = spread5((unsigned)gx) | (spread5((unsigned)gy) << 1) |
                 (spread5((unsigned)gz) << 2);                 // 15-bit Morton
    return ((unsigned)b << 15) | m;
}

__global__ void k_zero() {
    int t = blockIdx.x * 256 + threadIdx.x;
    if (t < NKEY) g_hist[t] = 0u;
}

__global__ void k_hist(const float* __restrict__ pts) {
    int n = blockIdx.x * 256 + threadIdx.x;
    if (n >= 2 * NPTS) return;
    const float* p = pts + (size_t)n * 3;
    int b = (n >= NPTS) ? 1 : 0;
    atomicAdd(&g_hist[cell_key(b, p[0], p[1], p[2])], 1u);
}

// One block per batch: exclusive scan of 32768 cell counts (batch base is known = b*NPTS).
__global__ void k_scan() {
    __shared__ unsigned part[1024];
    const int t = threadIdx.x;
    const unsigned base = (unsigned)blockIdx.x * 32768u + (unsigned)t * 32u;
    unsigned s = 0;
#pragma unroll
    for (int j = 0; j < 32; ++j) s += g_hist[base + j];
    part[t] = s;
    __syncthreads();
    for (int off = 1; off < 1024; off <<= 1) {
        unsigned v = (t >= off) ? part[t - off] : 0u;
        __syncthreads();
        part[t] += v;
        __syncthreads();
    }
    unsigned run = (unsigned)blockIdx.x * (unsigned)NPTS + part[t] - s;  // exclusive
#pragma unroll
    for (int j = 0; j < 32; ++j) {
        unsigned h = g_hist[base + j];
        g_hist[base + j] = run;   // becomes the atomic cursor for k_scatter
        run += h;
    }
}

__global__ void k_scatter(const float* __restrict__ pts) {
    int n = blockIdx.x * 256 + threadIdx.x;
    if (n >= 2 * NPTS) return;
    const float* p = pts + (size_t)n * 3;
    int b = (n >= NPTS) ? 1 : 0;
    float x = p[0], y = p[1], z = p[2];
    unsigned dst = atomicAdd(&g_hist[cell_key(b, x, y, z)], 1u);
    if (dst < 2u * NPTS)
        g_sorted[dst] = make_float4(x, y, z, __uint_as_float((unsigned)(n - b * NPTS)));
}

static __device__ __forceinline__ float wred_min(float v) {
#pragma unroll
    for (int off = 32; off > 0; off >>= 1) v = fminf(v, __shfl_xor(v, off, 64));
    return v;
}
static __device__ __forceinline__ float wred_max(float v) {
#pragma unroll
    for (int off = 32; off > 0; off >>= 1) v = fmaxf(v, __shfl_xor(v, off, 64));
    return v;
}

// One wave per 64 Morton-sorted points. Exact kNN(11) + Voronoi edge distance via a
// provably-conservative per-wave candidate shortlist:
//   s can be in any group point's top-11  =>  dist_box(s) <= d11(centroid) + R
// with d11(centroid) <= max of the 11 smallest of 64 disjoint per-lane candidate minima.
// Distance / edge formulas kept bit-identical to the verified brute-force kernel.
__global__ __launch_bounds__(64, 4) void voronoi_kernel(
    const float* __restrict__ spts,   // (2, NSP, 3)
    float* __restrict__ out)          // (2, NPTS)
{
    __shared__ float4 sl[CAP];

    const int b    = blockIdx.y;
    const int lane = threadIdx.x;
    int pi = blockIdx.x * 64 + lane;
    const bool valid = (pi < NPTS);
    if (!valid) pi = NPTS - 1;        // clamp: lanes stay active (full-wave ballots)

    const float4 P = g_sorted[(size_t)b * NPTS + pi];
    const float px = P.x, py = P.y, pz = P.z;
    const unsigned orig = __float_as_uint(P.w);

    // ---- wave bounding box + radius (from actual coords: exact regardless of sort) ----
    const float mnx = wred_min(px), mxx = wred_max(px);
    const float mny = wred_min(py), mxy = wred_max(py);
    const float mnz = wred_min(pz), mxz = wred_max(pz);
    const float ccx = 0.5f * (mnx + mxx);
    const float ccy = 0.5f * (mny + mxy);
    const float ccz = 0.5f * (mnz + mxz);
    const float R = sqrtf(wred_max(
        fmaf(px - ccx, px - ccx, fmaf(py - ccy, py - ccy, (pz - ccz) * (pz - ccz)))));

    const float4* __restrict__ spq = (const float4*)(spts + (size_t)b * NSP * 3);

    // ---- scan 1: per-lane min dist^2(candidate, center) over disjoint quad-groups ----
    float myMin = BIG;
#pragma unroll 2
    for (int k0 = 0; k0 < NGRP; k0 += 64) {
        const int g  = k0 + lane;
        const int gc = (g < NGRP) ? g : (NGRP - 1);
        const float4 q0 = spq[3 * gc + 0];
        const float4 q1 = spq[3 * gc + 1];
        const float4 q2 = spq[3 * gc + 2];
        float dx = q0.x - ccx, dy = q0.y - ccy, dz = q0.z - ccz;
        float md = fmaf(dx, dx, fmaf(dy, dy, dz * dz));
        dx = q0.w - ccx; dy = q1.x - ccy; dz = q1.y - ccz;
        md = fminf(md, fmaf(dx, dx, fmaf(dy, dy, dz * dz)));
        dx = q1.z - ccx; dy = q1.w - ccy; dz = q2.x - ccz;
        md = fminf(md, fmaf(dx, dx, fmaf(dy, dy, dz * dz)));
        dx = q2.y - ccx; dy = q2.z - ccy; dz = q2.w - ccz;
        md = fminf(md, fmaf(dx, dx, fmaf(dy, dy, dz * dz)));
        if (g < NGRP) myMin = fminf(myMin, md);   // guard keeps lane-sets disjoint
    }

    // ---- D_ub: 11 extract-min rounds over the 64 disjoint lane-mins ----
    float vv = myMin, m11 = 0.0f;
#pragma unroll
    for (int t = 0; t < KNN; ++t) {
        m11 = wred_min(vv);
        vv = (vv == m11) ? BIG : vv;   // ties: both removed, bound stays valid
    }
    const float Trad = sqrtf(m11) + R;
    const float T = Trad * Trad * 1.0004f + 1e-12f;   // fp-safety margin

    auto adm_test = [&](float sx, float sy, float sz) -> bool {
        const float tx = MED3(sx, mnx, mxx) - sx;     // closest-point-in-box delta
        const float ty = MED3(sy, mny, mxy) - sy;
        const float tz = MED3(sz, mnz, mxz) - sz;
        return fmaf(tx, tx, fmaf(ty, ty, tz * tz)) <= T;
    };

    unsigned cnt = 0;
    auto push = [&](float sx, float sy, float sz, bool ok, int idx) {
        const unsigned long long msk = __ballot(ok);
        const unsigned pos = cnt +
            __builtin_amdgcn_mbcnt_hi((unsigned)(msk >> 32),
                __builtin_amdgcn_mbcnt_lo((unsigned)msk, 0u));
        if (ok && pos < CAP)
            sl[pos] = make_float4(sx, sy, sz, __uint_as_float((unsigned)idx));
        cnt += (unsigned)__popcll(msk);
    };

    auto build = [&](int g0, int g1) -> unsigned {
        cnt = 0;
        for (int k0 = g0; k0 < g1; k0 += 64) {
            const int g  = k0 + lane;
            const int gc = (g < g1) ? g : (g1 - 1);
            const bool in = (g < g1);
            const float4 q0 = spq[3 * gc + 0];
            const float4 q1 = spq[3 * gc + 1];
            const float4 q2 = spq[3 * gc + 2];
            const bool a0 = in && adm_test(q0.x, q0.y, q0.z);
            const bool a1 = in && adm_test(q0.w, q1.x, q1.y);
            const bool a2 = in && adm_test(q1.z, q1.w, q2.x);
            const bool a3 = in && adm_test(q2.y, q2.z, q2.w);
            push(q0.x, q0.y, q0.z, a0, 4 * gc + 0);
            push(q0.w, q1.x, q1.y, a1, 4 * gc + 1);
            push(q1.z, q1.w, q2.x, a2, 4 * gc + 2);
            push(q2.y, q2.z, q2.w, a3, 4 * gc + 3);
        }
        return cnt;
    };

    // ---- pass A: exact top-11 med3 chain over the shortlist (broadcast ds_read) ----
    float d0 = BIG, d1 = BIG, d2 = BIG, d3 = BIG, d4 = BIG, d5 = BIG,
          d6 = BIG, d7 = BIG, d8 = BIG, d9 = BIG, d10 = BIG;
    int i0 = 0;

    auto chainA = [&](unsigned n) {
        if (n == 0u) return;
        float4 q = sl[0];
#pragma unroll 2
        for (unsigned k = 0; k < n; ++k) {
            const unsigned kn = (k + 1u < n) ? k + 1u : k;
            const float4 qn = sl[kn];                     // 1-ahead prefetch
            const float dx = px - q.x, dy = py - q.y, dz = pz - q.z;
            const float nd = fmaf(dx, dx, fmaf(dy, dy, dz * dz));
            const int jj = (int)__float_as_uint(q.w);
            d10 = MED3(d9, d10, nd);
            d9  = MED3(d8, d9,  nd);
            d8  = MED3(d7, d8,  nd);
            d7  = MED3(d6, d7,  nd);
            d6  = MED3(d5, d6,  nd);
            d5  = MED3(d4, d5,  nd);
            d4  = MED3(d3, d4,  nd);
            d3  = MED3(d2, d3,  nd);
            d2  = MED3(d1, d2,  nd);
            d1  = MED3(d0, d1,  nd);
            i0  = (nd < d0) ? jj : i0;
            d0  = fminf(d0, nd);
            q = qn;
        }
    };

    const unsigned total = build(0, NGRP);
    const bool fastp = (total <= CAP);      // wave-uniform
    if (fastp) {
        chainA(total);
    } else {
        for (int c = 0; c < NGRP; c += CAP / 4)           // chunk = CAP candidates
            chainA(build(c, min(c + CAP / 4, NGRP)));     //   -> can never overflow
    }

    // ---- pass B: edge distance over the same exact admissible set ----
    const float d10g = d10;
    const int   i0g  = i0;
    const float* ip = spts + (size_t)b * NSP * 3 + (size_t)(unsigned)i0g * 3;
    const float ix = ip[0], iy = ip[1], iz = ip[2];
    const float vx = px - ix, vy = py - iy, vz = pz - iz;
    float best = BIG;

    auto scanB = [&](unsigned n) {
        if (n == 0u) return;
        float4 q = sl[0];
#pragma unroll 2
        for (unsigned k = 0; k < n; ++k) {
            const unsigned kn = (k + 1u < n) ? k + 1u : k;
            const float4 qn = sl[kn];
            const float dx = px - q.x, dy = py - q.y, dz = pz - q.z;
            const float nd = fmaf(dx, dx, fmaf(dy, dy, dz * dz));
            const int jj = (int)__float_as_uint(q.w);
            const bool adm = (nd <= d10g) && (jj != i0g);
            const float ex = q.x - ix, ey = q.y - iy, ez = q.z - iz;
            const float ee = fmaf(ex, ex, fmaf(ey, ey, ez * ez));
            const float dt = fmaf(vx, ex, fmaf(vy, ey, vz * ez));
            const float u  = fmaf(-0.5f, ee, dt);
            const float t2 = u * u * __builtin_amdgcn_rcpf(ee);
            best = adm ? fminf(best, t2) : best;          // NaN (ee=0) masked by adm
            q = qn;
        }
    };

    if (fastp) {
        scanB(total);
    } else {
        for (int c = 0; c < NGRP; c += CAP / 4)
            scanB(build(c, min(c + CAP / 4, NGRP)));
    }

    if (valid) out[(size_t)b * NPTS + orig] = best;
}

extern "C" void kernel_launch(void* const* d_in, const int* in_sizes, int n_in,
                              void* d_out, int out_size, void* d_ws, size_t ws_size,
                              hipStream_t stream) {
    (void)in_sizes; (void)n_in; (void)d_ws; (void)ws_size; (void)out_size;
    const float* pts  = (const float*)d_in[0];   // (2, 50000, 3)
    const float* spts = (const float*)d_in[1];   // (2, 4000, 3)
    float* out = (float*)d_out;                  // (2, 50000)

    k_zero   <<<dim3(NKEY / 256),            dim3(256),  0, stream>>>();
    k_hist   <<<dim3((2 * NPTS + 255)/256),  dim3(256),  0, stream>>>(pts);
    k_scan   <<<dim3(2),                     dim3(1024), 0, stream>>>();
    k_scatter<<<dim3((2 * NPTS + 255)/256),  dim3(256),  0, stream>>>(pts);
    voronoi_kernel<<<dim3((NPTS + 63)/64, 2), dim3(64),  0, stream>>>(spts, out);
}

// Round 2
// 305.970 us; speedup vs baseline: 2.0837x; 2.0837x over previous
//
#include <hip/hip_runtime.h>
#include <math.h>

#define NPTS  50000
#define NSP   4000
#define NGRP  1000           // NSP/4 candidate quads
#define NW    4              // waves per 64-point group
#define QW    (NGRP / NW)    // 250 quads per wave
#define QC    (NSP  / NW)    // 1000 candidates per wave
#define KNN   11
#define BIG   3.4e38f
#define SEGCAP 256           // per-wave shortlist capacity
#define SEGPAD 8
#define SEGSTR (SEGCAP + SEGPAD)
#define GRIDC 32
#define NKEY  65536          // 2 batches * 32^3 cells

#define MED3(a,b,c) __builtin_amdgcn_fmed3f((a),(b),(c))

// Static scratch: counting-sort hist/offsets + sorted points.
__device__ unsigned g_hist[NKEY];
__device__ float4   g_sorted[2 * NPTS];   // (x,y,z, orig_idx_bits)

static __device__ __forceinline__ unsigned spread5(unsigned v) {
    return (v & 1u) | ((v & 2u) << 2) | ((v & 4u) << 4) |
           ((v & 8u) << 6) | ((v & 16u) << 8);
}

static __device__ __forceinline__ unsigned cell_key(int b, float x, float y, float z) {
    int gx = (int)floorf((x + 4.0f) * 4.0f);
    int gy = (int)floorf((y + 4.0f) * 4.0f);
    int gz = (int)floorf((z + 4.0f) * 4.0f);
    gx = min(max(gx, 0), GRIDC - 1);
    gy = min(max(gy, 0), GRIDC - 1);
    gz = min(max(gz, 0), GRIDC - 1);
    unsigned m = spread5((unsigned)gx) | (spread5((unsigned)gy) << 1) |
                 (spread5((unsigned)gz) << 2);
    return ((unsigned)b << 15) | m;
}

__global__ void k_zero() {
    int t = blockIdx.x * 256 + threadIdx.x;
    if (t < NKEY) g_hist[t] = 0u;
}

__global__ void k_hist(const float* __restrict__ pts) {
    int n = blockIdx.x * 256 + threadIdx.x;
    if (n >= 2 * NPTS) return;
    const float* p = pts + (size_t)n * 3;
    int b = (n >= NPTS) ? 1 : 0;
    atomicAdd(&g_hist[cell_key(b, p[0], p[1], p[2])], 1u);
}

__global__ void k_scan() {
    __shared__ unsigned part[1024];
    const int t = threadIdx.x;
    const unsigned base = (unsigned)blockIdx.x * 32768u + (unsigned)t * 32u;
    unsigned s = 0;
#pragma unroll
    for (int j = 0; j < 32; ++j) s += g_hist[base + j];
    part[t] = s;
    __syncthreads();
    for (int off = 1; off < 1024; off <<= 1) {
        unsigned v = (t >= off) ? part[t - off] : 0u;
        __syncthreads();
        part[t] += v;
        __syncthreads();
    }
    unsigned run = (unsigned)blockIdx.x * (unsigned)NPTS + part[t] - s;
#pragma unroll
    for (int j = 0; j < 32; ++j) {
        unsigned h = g_hist[base + j];
        g_hist[base + j] = run;
        run += h;
    }
}

__global__ void k_scatter(const float* __restrict__ pts) {
    int n = blockIdx.x * 256 + threadIdx.x;
    if (n >= 2 * NPTS) return;
    const float* p = pts + (size_t)n * 3;
    int b = (n >= NPTS) ? 1 : 0;
    float x = p[0], y = p[1], z = p[2];
    unsigned dst = atomicAdd(&g_hist[cell_key(b, x, y, z)], 1u);
    if (dst < 2u * NPTS)
        g_sorted[dst] = make_float4(x, y, z, __uint_as_float((unsigned)(n - b * NPTS)));
}

static __device__ __forceinline__ float wred_min(float v) {
#pragma unroll
    for (int off = 32; off > 0; off >>= 1) v = fminf(v, __shfl_xor(v, off, 64));
    return v;
}
static __device__ __forceinline__ float wred_max(float v) {
#pragma unroll
    for (int off = 32; off > 0; off >>= 1) v = fmaxf(v, __shfl_xor(v, off, 64));
    return v;
}

// Block = 4 waves x one 64-point Morton group. Each wave filters its QUARTER of the
// candidates through the conservative box test into its own LDS segment, chains it
// (exact med3 top-11), then the round-0 med3-union merge across the 4 waves yields the
// exact global top-11 per point. Pass B per wave over its quarter; min-merge at the end.
// Overflow waves (> SEGCAP admissible in their quarter) fall back to the verified
// round-0 brute chain over their 1000 candidates (scalar s_load stream, no LDS).
__global__ __launch_bounds__(256, 4) void voronoi_kernel(
    const float* __restrict__ spts,   // (2, NSP, 3)
    float* __restrict__ out)          // (2, NPTS)
{
    __shared__ float4 sl[NW * SEGSTR];      // 16.9 KiB shortlist segments
    __shared__ float  lds_d[NW][64][13];    // 13.3 KiB merge lists (stride 13: coprime 32)
    __shared__ int    lds_i[NW][64];
    __shared__ float  lds_b[NW][64];
    __shared__ float  lds_m[NW];

    const int b    = blockIdx.y;
    const int lane = threadIdx.x & 63;
    const int wq   = threadIdx.x >> 6;      // wave id = candidate quarter (wave-uniform)
    int pi = blockIdx.x * 64 + lane;
    const bool valid = (pi < NPTS);
    if (!valid) pi = NPTS - 1;              // clamp; lanes stay active

    const float4 P = g_sorted[(size_t)b * NPTS + pi];
    const float px = P.x, py = P.y, pz = P.z;
    const unsigned orig = __float_as_uint(P.w);

    // ---- group bbox + radius (identical in all 4 waves; exact regardless of sort) ----
    const float mnx = wred_min(px), mxx = wred_max(px);
    const float mny = wred_min(py), mxy = wred_max(py);
    const float mnz = wred_min(pz), mxz = wred_max(pz);
    const float ccx = 0.5f * (mnx + mxx);
    const float ccy = 0.5f * (mny + mxy);
    const float ccz = 0.5f * (mnz + mxz);
    const float R = sqrtf(wred_max(
        fmaf(px - ccx, px - ccx, fmaf(py - ccy, py - ccy, (pz - ccz) * (pz - ccz)))));

    const float4* __restrict__ spq = (const float4*)(spts + (size_t)b * NSP * 3);
    const int g0 = wq * QW, g1 = g0 + QW;

    // ---- D_ub: per-lane min over disjoint subsets of OWN quarter, 11 extract-mins.
    // 11th-extract over 64 disjoint lane-mins >= 11 distinct candidate dists
    //   => d11(centroid) <= m11_w for every wave; min over waves stays a valid bound.
    float myMin = BIG;
    for (int k0 = g0; k0 < g1; k0 += 64) {
        const int g  = k0 + lane;
        const int gc = (g < g1) ? g : (g1 - 1);
        const float4 q0 = spq[3 * gc + 0];
        const float4 q1 = spq[3 * gc + 1];
        const float4 q2 = spq[3 * gc + 2];
        float dx = q0.x - ccx, dy = q0.y - ccy, dz = q0.z - ccz;
        float md = fmaf(dx, dx, fmaf(dy, dy, dz * dz));
        dx = q0.w - ccx; dy = q1.x - ccy; dz = q1.y - ccz;
        md = fminf(md, fmaf(dx, dx, fmaf(dy, dy, dz * dz)));
        dx = q1.z - ccx; dy = q1.w - ccy; dz = q2.x - ccz;
        md = fminf(md, fmaf(dx, dx, fmaf(dy, dy, dz * dz)));
        dx = q2.y - ccx; dy = q2.z - ccy; dz = q2.w - ccz;
        md = fminf(md, fmaf(dx, dx, fmaf(dy, dy, dz * dz)));
        if (g < g1) myMin = fminf(myMin, md);
    }
    float vv = myMin, m11 = 0.0f;
#pragma unroll
    for (int t = 0; t < KNN; ++t) {
        m11 = wred_min(vv);
        vv = (vv == m11) ? BIG : vv;        // extra tie-removal only loosens (still valid)
    }
    if (lane == 0) lds_m[wq] = m11;
    __syncthreads();
    const float m11g = fminf(fminf(lds_m[0], lds_m[1]), fminf(lds_m[2], lds_m[3]));
    const float Trad = sqrtf(m11g) + R;
    const float T = Trad * Trad * 1.0004f + 1e-12f;   // fp-safety margin

    // ---- build own shortlist segment (wave-local ballot compaction) ----
    const int segbase = wq * SEGSTR;
    unsigned cnt = 0;
    {
        for (int k0 = g0; k0 < g1; k0 += 64) {
            const int g  = k0 + lane;
            const int gc = (g < g1) ? g : (g1 - 1);
            const bool in = (g < g1);
            const float4 q0 = spq[3 * gc + 0];
            const float4 q1 = spq[3 * gc + 1];
            const float4 q2 = spq[3 * gc + 2];
#define ADM(sx, sy, sz) \
            (fmaf(MED3((sx), mnx, mxx) - (sx), MED3((sx), mnx, mxx) - (sx), \
             fmaf(MED3((sy), mny, mxy) - (sy), MED3((sy), mny, mxy) - (sy), \
                  (MED3((sz), mnz, mxz) - (sz)) * (MED3((sz), mnz, mxz) - (sz)))) <= T)
#define PUSH(sx, sy, sz, ok, idx) { \
            const unsigned long long msk = __ballot(ok); \
            const unsigned pos = cnt + \
                __builtin_amdgcn_mbcnt_hi((unsigned)(msk >> 32), \
                    __builtin_amdgcn_mbcnt_lo((unsigned)msk, 0u)); \
            if ((ok) && pos < SEGCAP) \
                sl[segbase + pos] = make_float4((sx), (sy), (sz), \
                                                __uint_as_float((unsigned)(idx))); \
            cnt += (unsigned)__popcll(msk); }
            const bool a0 = in && ADM(q0.x, q0.y, q0.z);
            const bool a1 = in && ADM(q0.w, q1.x, q1.y);
            const bool a2 = in && ADM(q1.z, q1.w, q2.x);
            const bool a3 = in && ADM(q2.y, q2.z, q2.w);
            PUSH(q0.x, q0.y, q0.z, a0, 4 * gc + 0);
            PUSH(q0.w, q1.x, q1.y, a1, 4 * gc + 1);
            PUSH(q1.z, q1.w, q2.x, a2, 4 * gc + 2);
            PUSH(q2.y, q2.z, q2.w, a3, 4 * gc + 3);
        }
        // sentinel pad: 8 entries cover round-up + 4-deep read-ahead
        if (lane < SEGPAD) {
            const unsigned cb = (cnt <= SEGCAP) ? cnt : SEGCAP;
            sl[segbase + cb + lane] =
                make_float4(1e18f, 1e18f, 1e18f, __uint_as_float(0x7fffffffu));
        }
    }
    const bool myfast = (cnt <= SEGCAP);    // wave-uniform

    // ---- pass A: exact top-11 med3 chain ----
    float d0 = BIG, d1 = BIG, d2 = BIG, d3 = BIG, d4 = BIG, d5 = BIG,
          d6 = BIG, d7 = BIG, d8 = BIG, d9 = BIG, d10 = BIG;
    int i0 = 0x7fffffff;

#define CHAIN(nd, jj) { \
        if (__ballot((nd) < d10)) { \
            d10 = MED3(d9, d10, (nd)); \
            d9  = MED3(d8, d9,  (nd)); \
            d8  = MED3(d7, d8,  (nd)); \
            d7  = MED3(d6, d7,  (nd)); \
            d6  = MED3(d5, d6,  (nd)); \
            d5  = MED3(d4, d5,  (nd)); \
            d4  = MED3(d3, d4,  (nd)); \
            d3  = MED3(d2, d3,  (nd)); \
            d2  = MED3(d1, d2,  (nd)); \
            d1  = MED3(d0, d1,  (nd)); \
            i0  = ((nd) < d0) ? (jj) : i0; \
            d0  = fminf(d0, (nd)); \
        } }
#define CANDA(c) { \
        const float dx = px - (c).x, dy = py - (c).y, dz = pz - (c).z; \
        const float nd = fmaf(dx, dx, fmaf(dy, dy, dz * dz)); \
        const int jj = (int)__float_as_uint((c).w); \
        CHAIN(nd, jj); }

    const float* sp = spts + (size_t)b * NSP * 3 + wq * (QC * 3);  // uniform (brute path)
    const int jb = wq * QC;

    if (myfast) {
        if (cnt > 0) {
            float4 c0 = sl[segbase + 0], c1 = sl[segbase + 1],
                   c2 = sl[segbase + 2], c3 = sl[segbase + 3];
            for (unsigned k = 0; k < cnt; k += 4) {       // 4-deep ds_read pipeline
                const float4 n0 = sl[segbase + k + 4];
                const float4 n1 = sl[segbase + k + 5];
                const float4 n2 = sl[segbase + k + 6];
                const float4 n3 = sl[segbase + k + 7];
                CANDA(c0); CANDA(c1); CANDA(c2); CANDA(c3);
                c0 = n0; c1 = n1; c2 = n2; c3 = n3;
            }
        }
    } else {
        // brute: round-0 chain over own quarter, scalar s_load candidate stream
        for (int j = 0; j < QC; j += 4) {
            const float4 q0 = *(const float4*)(sp + j * 3);
            const float4 q1 = *(const float4*)(sp + j * 3 + 4);
            const float4 q2 = *(const float4*)(sp + j * 3 + 8);
            { const float dx = px - q0.x, dy = py - q0.y, dz = pz - q0.z;
              const float nd = fmaf(dx, dx, fmaf(dy, dy, dz * dz)); CHAIN(nd, jb + j); }
            { const float dx = px - q0.w, dy = py - q1.x, dz = pz - q1.y;
              const float nd = fmaf(dx, dx, fmaf(dy, dy, dz * dz)); CHAIN(nd, jb + j + 1); }
            { const float dx = px - q1.z, dy = py - q1.w, dz = pz - q2.x;
              const float nd = fmaf(dx, dx, fmaf(dy, dy, dz * dz)); CHAIN(nd, jb + j + 2); }
            { const float dx = px - q2.y, dy = py - q2.z, dz = pz - q2.w;
              const float nd = fmaf(dx, dx, fmaf(dy, dy, dz * dz)); CHAIN(nd, jb + j + 3); }
        }
    }

    // ---- publish + exact union merge across the 4 waves (round-0 verified code) ----
    lds_d[wq][lane][0]  = d0;  lds_d[wq][lane][1]  = d1;
    lds_d[wq][lane][2]  = d2;  lds_d[wq][lane][3]  = d3;
    lds_d[wq][lane][4]  = d4;  lds_d[wq][lane][5]  = d5;
    lds_d[wq][lane][6]  = d6;  lds_d[wq][lane][7]  = d7;
    lds_d[wq][lane][8]  = d8;  lds_d[wq][lane][9]  = d9;
    lds_d[wq][lane][10] = d10;
    lds_i[wq][lane] = i0;
    __syncthreads();

    float gb = BIG; int gi = 0x7fffffff;
#pragma unroll
    for (int q = 0; q < NW; ++q) {
        const float dq = lds_d[q][lane][0];
        const int   iq = lds_i[q][lane];
        const bool take = (dq < gb) || (dq == gb && iq < gi);
        gb = take ? dq : gb;
        gi = take ? iq : gi;
    }
#define INS(v) { \
        d10 = MED3(d9, d10, (v)); \
        d9  = MED3(d8, d9,  (v)); \
        d8  = MED3(d7, d8,  (v)); \
        d7  = MED3(d6, d7,  (v)); \
        d6  = MED3(d5, d6,  (v)); \
        d5  = MED3(d4, d5,  (v)); \
        d4  = MED3(d3, d4,  (v)); \
        d3  = MED3(d2, d3,  (v)); \
        d2  = MED3(d1, d2,  (v)); \
        d1  = MED3(d0, d1,  (v)); \
        d0  = fminf(d0, (v)); }
#pragma unroll
    for (int q = 0; q < NW; ++q) {
        if (q == wq) continue;
#pragma unroll
        for (int k = 0; k < 11; ++k) INS(lds_d[q][lane][k]);
    }
    const float d10g = d10;                 // exact union 11th-smallest
    const int   i0g  = gi;                  // exact lexicographic argmin

    // ---- pass B: edge distance over own quarter's admissible set ----
    const float* ip = spts + (size_t)b * NSP * 3 + (size_t)(unsigned)i0g * 3;
    const float ix = ip[0], iy = ip[1], iz = ip[2];
    const float vx = px - ix, vy = py - iy, vz = pz - iz;
    float best = BIG;

#define EDGE(sx, sy, sz, adm) { \
        if (__ballot(adm)) { \
            const float ex = (sx) - ix, ey = (sy) - iy, ez = (sz) - iz; \
            const float ee = fmaf(ex, ex, fmaf(ey, ey, ez * ez)); \
            const float dt = fmaf(vx, ex, fmaf(vy, ey, vz * ez)); \
            const float u  = fmaf(-0.5f, ee, dt); \
            const float t2 = u * u * __builtin_amdgcn_rcpf(ee); \
            best = (adm) ? fminf(best, t2) : best; \
        } }
#define CANDB(c) { \
        const float dx = px - (c).x, dy = py - (c).y, dz = pz - (c).z; \
        const float nd = fmaf(dx, dx, fmaf(dy, dy, dz * dz)); \
        const int jj = (int)__float_as_uint((c).w); \
        const bool adm = (nd <= d10g) && (jj != i0g); \
        EDGE((c).x, (c).y, (c).z, adm); }

    if (myfast) {
        if (cnt > 0) {
            float4 c0 = sl[segbase + 0], c1 = sl[segbase + 1],
                   c2 = sl[segbase + 2], c3 = sl[segbase + 3];
            for (unsigned k = 0; k < cnt; k += 4) {
                const float4 n0 = sl[segbase + k + 4];
                const float4 n1 = sl[segbase + k + 5];
                const float4 n2 = sl[segbase + k + 6];
                const float4 n3 = sl[segbase + k + 7];
                CANDB(c0); CANDB(c1); CANDB(c2); CANDB(c3);
                c0 = n0; c1 = n1; c2 = n2; c3 = n3;
            }
        }
    } else {
        for (int j = 0; j < QC; j += 4) {
            const float4 q0 = *(const float4*)(sp + j * 3);
            const float4 q1 = *(const float4*)(sp + j * 3 + 4);
            const float4 q2 = *(const float4*)(sp + j * 3 + 8);
            { const float dx = px - q0.x, dy = py - q0.y, dz = pz - q0.z;
              const float nd = fmaf(dx, dx, fmaf(dy, dy, dz * dz));
              const bool adm = (nd <= d10g) && ((jb + j) != i0g);
              EDGE(q0.x, q0.y, q0.z, adm); }
            { const float dx = px - q0.w, dy = py - q1.x, dz = pz - q1.y;
              const float nd = fmaf(dx, dx, fmaf(dy, dy, dz * dz));
              const bool adm = (nd <= d10g) && ((jb + j + 1) != i0g);
              EDGE(q0.w, q1.x, q1.y, adm); }
            { const float dx = px - q1.z, dy = py - q1.w, dz = pz - q2.x;
              const float nd = fmaf(dx, dx, fmaf(dy, dy, dz * dz));
              const bool adm = (nd <= d10g) && ((jb + j + 2) != i0g);
              EDGE(q1.z, q1.w, q2.x, adm); }
            { const float dx = px - q2.y, dy = py - q2.z, dz = pz - q2.w;
              const float nd = fmaf(dx, dx, fmaf(dy, dy, dz * dz));
              const bool adm = (nd <= d10g) && ((jb + j + 3) != i0g);
              EDGE(q2.y, q2.z, q2.w, adm); }
        }
    }

    // ---- final min across the 4 waves ----
    lds_b[wq][lane] = best;
    __syncthreads();
    if (wq == 0) {
        float m = fminf(fminf(lds_b[0][lane], lds_b[1][lane]),
                        fminf(lds_b[2][lane], lds_b[3][lane]));
        if (valid) out[(size_t)b * NPTS + orig] = m;
    }
}

extern "C" void kernel_launch(void* const* d_in, const int* in_sizes, int n_in,
                              void* d_out, int out_size, void* d_ws, size_t ws_size,
                              hipStream_t stream) {
    (void)in_sizes; (void)n_in; (void)d_ws; (void)ws_size; (void)out_size;
    const float* pts  = (const float*)d_in[0];   // (2, 50000, 3)
    const float* spts = (const float*)d_in[1];   // (2, 4000, 3)
    float* out = (float*)d_out;                  // (2, 50000)

    k_zero   <<<dim3(NKEY / 256),            dim3(256),  0, stream>>>();
    k_hist   <<<dim3((2 * NPTS + 255)/256),  dim3(256),  0, stream>>>(pts);
    k_scan   <<<dim3(2),                     dim3(1024), 0, stream>>>();
    k_scatter<<<dim3((2 * NPTS + 255)/256),  dim3(256),  0, stream>>>(pts);
    voronoi_kernel<<<dim3((NPTS + 63)/64, 2), dim3(256), 0, stream>>>(spts, out);
}